// Round 4
// baseline (46927.420 us; speedup 1.0000x reference)
//
#include <hip/hip_runtime.h>
#include <hip/hip_bf16.h>
#include <cstdint>
#include <cstddef>

#define T_STEPS 16384
#define HID 512
#define NSLOTS 32       // worker WGs (512 thr = 8 waves each; wave owns 2 h-elems)
#define NLAUNCH 256     // over-launch; round-robin puts ~32 WGs on each XCD

typedef float f32x4 __attribute__((ext_vector_type(4)));
typedef float f32x2 __attribute__((ext_vector_type(2)));

// ---------------------------------------------------------------------------
// 64-lane sum via DPP (VALU pipe). Result valid in lane 63.
// ---------------------------------------------------------------------------
__device__ __forceinline__ float wave_reduce_sum(float x) {
#define DPP_ADD(ctrl)                                                          \
  x += __int_as_float(__builtin_amdgcn_update_dpp(                             \
      0, __float_as_int(x), (ctrl), 0xF, 0xF, true))
  DPP_ADD(0x111);  // row_shr:1
  DPP_ADD(0x112);  // row_shr:2
  DPP_ADD(0x114);  // row_shr:4
  DPP_ADD(0x118);  // row_shr:8
  DPP_ADD(0x142);  // row_bcast:15
  DPP_ADD(0x143);  // row_bcast:31 -> lane63 = total
#undef DPP_ADD
  return x;
}

__device__ __forceinline__ float fsigmoid(float x) {
  return __builtin_amdgcn_rcpf(1.f + __expf(-x));
}
__device__ __forceinline__ float ftanh(float x) {
  return 1.f - 2.f * __builtin_amdgcn_rcpf(1.f + __expf(2.f * x));
}

// ---------------------------------------------------------------------------
// Poll 8 floats (2 x dwordx4 per lane): near = sc0 (XCD-local L2 coherence),
// far = sc0 sc1 (L3/device coherence). Loads + vmcnt in ONE asm block.
// ---------------------------------------------------------------------------
__device__ __forceinline__ void poll_near(const float* a, f32x4& x, f32x4& y) {
  f32x4 u, v;
  asm volatile(
      "global_load_dwordx4 %0, %[p], off sc0\n\t"
      "global_load_dwordx4 %1, %[p], off offset:1024 sc0\n\t"
      "s_waitcnt vmcnt(0)"
      : "=&v"(u), "=&v"(v) : [p] "v"(a) : "memory");
  x = u; y = v;
}
__device__ __forceinline__ void poll_far(const float* a, f32x4& x, f32x4& y) {
  f32x4 u, v;
  asm volatile(
      "global_load_dwordx4 %0, %[p], off sc0 sc1\n\t"
      "global_load_dwordx4 %1, %[p], off offset:1024 sc0 sc1\n\t"
      "s_waitcnt vmcnt(0)"
      : "=&v"(u), "=&v"(v) : [p] "v"(a) : "memory");
  x = u; y = v;
}
__device__ __forceinline__ void pub_near(float* a, float x, float y) {
  f32x2 v; v.x = x; v.y = y;
  asm volatile("global_store_dwordx2 %0, %1, off sc0" :: "v"(a), "v"(v) : "memory");
}
__device__ __forceinline__ void pub_far(float* a, float x, float y) {
  f32x2 v; v.x = x; v.y = y;
  asm volatile("global_store_dwordx2 %0, %1, off sc0 sc1" :: "v"(a), "v"(v) : "memory");
}

// ---------------------------------------------------------------------------
// Prep: hsz[0][:]=0 (h0), hsz[1..T][:]=sentinel 2.0f (|h|<1 strictly -> 2.0 is
// an unreachable value-sync token). bc = w_ih@enc_b + b_ih.
// ctrl: [0]=counter, [1..256]=census(-1), [257..512]=assign(-2).
// ---------------------------------------------------------------------------
__global__ void k_prep(float* __restrict__ hsz, float* __restrict__ bc,
                       int* __restrict__ ctrl,
                       const float* __restrict__ w_ih,
                       const float* __restrict__ enc_b,
                       const float* __restrict__ b_ih) {
  const int gid = blockIdx.x * blockDim.x + threadIdx.x;
  const int gsz = gridDim.x * blockDim.x;
  float4* h4 = reinterpret_cast<float4*>(hsz);
  const float4 zer = make_float4(0.f, 0.f, 0.f, 0.f);
  const float4 sen = make_float4(2.f, 2.f, 2.f, 2.f);
  const int n4 = (T_STEPS + 1) * HID / 4;
  for (int i = gid; i < n4; i += gsz) h4[i] = (i < HID / 4) ? zer : sen;
  if (gid == 0) ctrl[0] = 0;
  if (gid >= 1 && gid < 1 + NLAUNCH) ctrl[gid] = -1;                 // census
  if (gid >= 1 + NLAUNCH && gid < 1 + 2 * NLAUNCH) ctrl[gid] = -2;   // assign
  if (gid < 3 * HID) {
    float acc = b_ih[gid];
    const float* wr = w_ih + (size_t)gid * HID;
    for (int j = 0; j < HID; ++j) acc = fmaf(wr[j], enc_b[j], acc);
    bc[gid] = acc;
  }
}

// ---------------------------------------------------------------------------
// 512x512 f32 transpose (enc_w -> enc_w^T).
// ---------------------------------------------------------------------------
__global__ void k_transpose512(const float* __restrict__ in, float* __restrict__ out) {
  __shared__ float tile[32][33];
  const int bx = blockIdx.x * 32, by = blockIdx.y * 32;
  const int x = threadIdx.x, y = threadIdx.y;  // block (32,8)
#pragma unroll
  for (int i = 0; i < 32; i += 8) tile[y + i][x] = in[(size_t)(by + y + i) * 512 + bx + x];
  __syncthreads();
#pragma unroll
  for (int i = 0; i < 32; i += 8) out[(size_t)(bx + y + i) * 512 + by + x] = tile[x][y + i];
}

// ---------------------------------------------------------------------------
// f32 GEMM, C[M,N] = A[M,K] @ B[N,K]^T (+ bias[n]); out f32 or bf16.
// ---------------------------------------------------------------------------
template <bool ADD_BIAS, bool OUT_BF16>
__global__ __launch_bounds__(256) void k_gemm_bt(
    const float* __restrict__ A, const float* __restrict__ B,
    const float* __restrict__ bias, void* __restrict__ C,
    int M, int N, int K) {
  __shared__ float As[16][68];
  __shared__ float Bs[16][68];
  const int n0 = blockIdx.x * 64;
  const int m0 = blockIdx.y * 64;
  const int tid = (int)threadIdx.x;
  const int tx = tid & 15, ty = tid >> 4;
  const int lr = tid >> 2;
  const int lc = (tid & 3) * 4;

  float acc[4][4] = {};
  for (int k0 = 0; k0 < K; k0 += 16) {
    const float4 a4 = *reinterpret_cast<const float4*>(A + (size_t)(m0 + lr) * K + k0 + lc);
    const float4 b4 = *reinterpret_cast<const float4*>(B + (size_t)(n0 + lr) * K + k0 + lc);
    __syncthreads();
    As[lc + 0][lr] = a4.x; As[lc + 1][lr] = a4.y; As[lc + 2][lr] = a4.z; As[lc + 3][lr] = a4.w;
    Bs[lc + 0][lr] = b4.x; Bs[lc + 1][lr] = b4.y; Bs[lc + 2][lr] = b4.z; Bs[lc + 3][lr] = b4.w;
    __syncthreads();
#pragma unroll
    for (int kk = 0; kk < 16; ++kk) {
      const float4 av = *reinterpret_cast<const float4*>(&As[kk][ty * 4]);
      const float4 bv = *reinterpret_cast<const float4*>(&Bs[kk][tx * 4]);
      const float a[4] = {av.x, av.y, av.z, av.w};
      const float b[4] = {bv.x, bv.y, bv.z, bv.w};
#pragma unroll
      for (int i = 0; i < 4; ++i)
#pragma unroll
        for (int j = 0; j < 4; ++j) acc[i][j] = fmaf(a[i], b[j], acc[i][j]);
    }
  }

  float bv[4] = {0.f, 0.f, 0.f, 0.f};
  if (ADD_BIAS) {
#pragma unroll
    for (int j = 0; j < 4; ++j) bv[j] = bias[n0 + tx * 4 + j];
  }
#pragma unroll
  for (int i = 0; i < 4; ++i) {
    const int m = m0 + ty * 4 + i;
    if (OUT_BF16) {
      __hip_bfloat16* Cb = (__hip_bfloat16*)C;
#pragma unroll
      for (int j = 0; j < 4; ++j)
        Cb[(size_t)m * N + n0 + tx * 4 + j] = __float2bfloat16(acc[i][j] + bv[j]);
    } else {
      float4 v;
      v.x = acc[i][0] + bv[0]; v.y = acc[i][1] + bv[1];
      v.z = acc[i][2] + bv[2]; v.w = acc[i][3] + bv[3];
      *reinterpret_cast<float4*>((float*)C + (size_t)m * N + n0 + tx * 4) = v;
    }
  }
}

// ---------------------------------------------------------------------------
// Scan main loop. Wave wid owns h elems {2wid, 2wid+1}. Lane L holds h slots
// {4L..4L+3} and {256+4L..256+4L+3} (dwordx4-friendly). XL: near (L2) sync
// with escalation watchdog -> self-heals to far (L3) sync if placement was
// wrong (idempotent value-republish; per-float monotone sentinel->value).
// ---------------------------------------------------------------------------
template <bool XL>
__device__ void scan_loop(int wid, int lane,
                          const float* __restrict__ w_hh,
                          const uint32_t* __restrict__ ig32,
                          const float* __restrict__ b_n,
                          float* __restrict__ hsz) {
  const int e0 = wid * 2;

  // wA[i] pairs h[4*lane + c]; wB[i] pairs h[256 + 4*lane + c].
  // rows: i0:r/e0 i1:r/e1 i2:z/e0 i3:z/e1 i4:n/e0 i5:n/e1
  f32x4 wA[6], wB[6];
#pragma unroll
  for (int i = 0; i < 6; ++i) {
    const float* wrow = w_hh + (size_t)((i >> 1) * HID + e0 + (i & 1)) * HID;
#pragma unroll
    for (int c = 0; c < 4; ++c) {
      wA[i][c] = wrow[4 * lane + c];
      wB[i][c] = wrow[256 + 4 * lane + c];
    }
  }

  float bn0 = 0.f, bn1 = 0.f, h0 = 0.f, h1 = 0.f;
  if (lane == 63) { bn0 = b_n[e0]; bn1 = b_n[e0 + 1]; }

  // ig pipeline, two steps deep (named regs; no runtime indexing).
  uint32_t gAr = 0, gAz = 0, gAn = 0, gBr = 0, gBz = 0, gBn = 0;
  if (lane == 63) {
    const uint32_t* r0 = ig32 + (e0 >> 1);
    gAr = r0[0]; gAz = r0[256]; gAn = r0[512];
    const uint32_t* r1 = r0 + 768;
    gBr = r1[0]; gBz = r1[256]; gBn = r1[512];
  }

  bool esc = false;  // latched escalation (only meaningful when XL)

#pragma unroll 1
  for (int t = 0; t < T_STEPS; ++t) {
    asm volatile("" : "+v"(wA[0]), "+v"(wA[1]), "+v"(wA[2]), "+v"(wA[3]),
                      "+v"(wA[4]), "+v"(wA[5]), "+v"(wB[0]), "+v"(wB[1]),
                      "+v"(wB[2]), "+v"(wB[3]), "+v"(wB[4]), "+v"(wB[5]));

    f32x4 hva = {0.f, 0.f, 0.f, 0.f}, hvb = {0.f, 0.f, 0.f, 0.f};
    if (t > 0) {
      const float* p = hsz + (size_t)t * HID + 4 * lane;
      hva = (f32x4)2.f; hvb = (f32x4)2.f;
      int iters = 0;
      for (;;) {
        bool nearpass = XL && (!esc || (iters & 1));
        f32x4 ta, tb;
        if (nearpass) poll_near(p, ta, tb); else poll_far(p, ta, tb);
        // monotone merge: keep first-seen real value, retry sentinels
#pragma unroll
        for (int c = 0; c < 4; ++c) {
          hva[c] = (hva[c] < 1.5f) ? hva[c] : ta[c];
          hvb[c] = (hvb[c] < 1.5f) ? hvb[c] : tb[c];
        }
        bool ok = (hva[0] < 1.5f) & (hva[1] < 1.5f) & (hva[2] < 1.5f) &
                  (hva[3] < 1.5f) & (hvb[0] < 1.5f) & (hvb[1] < 1.5f) &
                  (hvb[2] < 1.5f) & (hvb[3] < 1.5f);
        if (__all(ok)) break;
        ++iters;
        if (XL && !esc && iters > 400) {  // ~50us; legit skew is ~3 iters
          esc = true;  // self-heal: our last slice may be stranded in a
          if (lane == 63) pub_far(hsz + (size_t)t * HID + e0, h0, h1);
        }
      }
    }

    // issue ig row t+2 now; lands during compute + next poll (vmcnt-clean)
    uint32_t gCr = 0, gCz = 0, gCn = 0;
    if (lane == 63) {
      const int tn = (t + 2 < T_STEPS) ? t + 2 : T_STEPS - 1;
      const uint32_t* rn = ig32 + (size_t)tn * 768 + (e0 >> 1);
      gCr = rn[0]; gCz = rn[256]; gCn = rn[512];
    }

    float s0, s1, s2, s3, s4, s5;
    {
      float a;
#define ROWDOT(i, dst)                                                         \
      a = 0.f;                                                                 \
      a = fmaf(wA[i][0], hva[0], a); a = fmaf(wA[i][1], hva[1], a);            \
      a = fmaf(wA[i][2], hva[2], a); a = fmaf(wA[i][3], hva[3], a);            \
      a = fmaf(wB[i][0], hvb[0], a); a = fmaf(wB[i][1], hvb[1], a);            \
      a = fmaf(wB[i][2], hvb[2], a); a = fmaf(wB[i][3], hvb[3], a);            \
      dst = wave_reduce_sum(a)
      ROWDOT(0, s0); ROWDOT(1, s1); ROWDOT(2, s2);
      ROWDOT(3, s3); ROWDOT(4, s4); ROWDOT(5, s5);
#undef ROWDOT
    }

    if (lane == 63) {
      const float ir0 = __uint_as_float(gAr << 16);
      const float ir1 = __uint_as_float(gAr & 0xffff0000u);
      const float iz0 = __uint_as_float(gAz << 16);
      const float iz1 = __uint_as_float(gAz & 0xffff0000u);
      const float in0 = __uint_as_float(gAn << 16);
      const float in1 = __uint_as_float(gAn & 0xffff0000u);

      const float r0 = fsigmoid(ir0 + s0);
      const float r1 = fsigmoid(ir1 + s1);
      const float z0 = fsigmoid(iz0 + s2);
      const float z1 = fsigmoid(iz1 + s3);
      const float n0 = ftanh(in0 + r0 * (s4 + bn0));
      const float n1 = ftanh(in1 + r1 * (s5 + bn1));
      h0 = n0 + z0 * (h0 - n0);
      h1 = n1 + z1 * (h1 - n1);

      float* dst = hsz + (size_t)(t + 1) * HID + e0;
      if (XL && !esc) pub_near(dst, h0, h1); else pub_far(dst, h0, h1);
    }

    gAr = gBr; gAz = gBz; gAn = gBn;
    gBr = gCr; gBz = gCz; gBn = gCn;
  }
}

// ---------------------------------------------------------------------------
// Persistent scan with single-leader census placement.
// All WGs: census[bid]=xcc, release-inc counter, then poll assign[bid].
// Leader (bid 0): wait counter==NLAUNCH (deadline 200us, but never proceed
// with <NSLOTS present), histogram XCDs, pick one with >=NSLOTS WGs (mode 1)
// else first NSLOTS present (mode 0); write assign for ALL bids. Terminating
// by construction; scan self-heals if XCC info was wrong.
// ---------------------------------------------------------------------------
__global__ __launch_bounds__(512) void k_scan(
    const float* __restrict__ w_hh, const __hip_bfloat16* __restrict__ igb,
    const float* __restrict__ b_n, float* __restrict__ hsz,
    int* __restrict__ ctrl) {
  int* counter = ctrl;
  int* census  = ctrl + 1;
  int* assign  = ctrl + 1 + NLAUNCH;
  __shared__ int s_assign;

  int myxcc;
  asm("s_getreg_b32 %0, hwreg(HW_REG_XCC_ID)" : "=s"(myxcc));
  const int bid = (int)blockIdx.x;

  if (threadIdx.x == 0) {
    __hip_atomic_store(&census[bid], myxcc, __ATOMIC_RELAXED,
                       __HIP_MEMORY_SCOPE_AGENT);
    __hip_atomic_fetch_add(counter, 1, __ATOMIC_RELEASE,
                           __HIP_MEMORY_SCOPE_AGENT);
    if (bid == 0) {
      const uint64_t t0 = __builtin_amdgcn_s_memrealtime();
      int cnt;
      for (;;) {
        cnt = __hip_atomic_load(counter, __ATOMIC_ACQUIRE,
                                __HIP_MEMORY_SCOPE_AGENT);
        if (cnt >= NLAUNCH) break;
        if (cnt >= NSLOTS &&
            (__builtin_amdgcn_s_memrealtime() - t0) > 20000) break;  // ~200us
      }
      int hist[8] = {0, 0, 0, 0, 0, 0, 0, 0};
      for (int i = 0; i < NLAUNCH; ++i) {
        int c = __hip_atomic_load(&census[i], __ATOMIC_RELAXED,
                                  __HIP_MEMORY_SCOPE_AGENT);
        if (c >= 0 && c < 8) ++hist[c];
      }
      int pick = -1;
      for (int x = 0; x < 8; ++x)
        if (pick < 0 && hist[x] >= NSLOTS) pick = x;
      const int mode = (pick >= 0) ? 1 : 0;
      int slot = 0;
      for (int i = 0; i < NLAUNCH; ++i) {
        int c = __hip_atomic_load(&census[i], __ATOMIC_RELAXED,
                                  __HIP_MEMORY_SCOPE_AGENT);
        int a = -1;
        const bool take = (pick >= 0) ? (c == pick) : (c >= 0);
        if (take && slot < NSLOTS) { a = slot * 2 + mode; ++slot; }
        __hip_atomic_store(&assign[i], a, __ATOMIC_RELAXED,
                           __HIP_MEMORY_SCOPE_AGENT);
      }
    }
    int a;
    do {
      a = __hip_atomic_load(&assign[bid], __ATOMIC_ACQUIRE,
                            __HIP_MEMORY_SCOPE_AGENT);
    } while (a == -2);
    s_assign = a;
  }
  __syncthreads();
  const int a = s_assign;
  if (a < 0) return;
  const int slot = a >> 1, mode = a & 1;

  const int wid = slot * 8 + ((int)threadIdx.x >> 6);  // 0..255
  const int lane = (int)threadIdx.x & 63;
  const uint32_t* ig32 = reinterpret_cast<const uint32_t*>(igb);

  if (mode) scan_loop<true>(wid, lane, w_hh, ig32, b_n, hsz);
  else      scan_loop<false>(wid, lane, w_hh, ig32, b_n, hsz);
}

// ---------------------------------------------------------------------------
extern "C" void kernel_launch(void* const* d_in, const int* in_sizes, int n_in,
                              void* d_out, int out_size, void* d_ws, size_t ws_size,
                              hipStream_t stream) {
  (void)in_sizes; (void)n_in; (void)out_size; (void)ws_size;
  const float* x     = (const float*)d_in[0];
  const float* enc_w = (const float*)d_in[1];
  const float* enc_b = (const float*)d_in[2];
  const float* w_ih  = (const float*)d_in[3];
  const float* w_hh  = (const float*)d_in[4];
  const float* b_ih  = (const float*)d_in[5];
  const float* b_n   = (const float*)d_in[6];
  const float* dec_w = (const float*)d_in[7];
  const float* dec_b = (const float*)d_in[8];
  float* out = (float*)d_out;

  uintptr_t p = (uintptr_t)d_ws;
  auto carve = [&](size_t bytes) {
    void* r = (void*)p;
    p += (bytes + 255) & ~(size_t)255;
    return r;
  };
  int* ctrl           = (int*)carve((size_t)(1 + 2 * NLAUNCH) * 4);
  float* encwT        = (float*)carve((size_t)512 * 512 * 4);
  float* Wc           = (float*)carve((size_t)1536 * 512 * 4);
  float* bc           = (float*)carve((size_t)1536 * 4);
  __hip_bfloat16* igb = (__hip_bfloat16*)carve((size_t)T_STEPS * 1536 * 2);
  float* hsz          = (float*)carve((size_t)(T_STEPS + 1) * HID * 4);

  k_prep<<<1024, 256, 0, stream>>>(hsz, bc, ctrl, w_ih, enc_b, b_ih);
  k_transpose512<<<dim3(16, 16), dim3(32, 8), 0, stream>>>(enc_w, encwT);
  k_gemm_bt<false, false><<<dim3(512 / 64, 1536 / 64), 256, 0, stream>>>(
      w_ih, encwT, nullptr, Wc, 1536, 512, 512);
  k_gemm_bt<true, true><<<dim3(1536 / 64, 16384 / 64), 256, 0, stream>>>(
      x, Wc, bc, igb, T_STEPS, 1536, 512);
  k_scan<<<NLAUNCH, 512, 0, stream>>>(w_hh, igb, b_n, hsz, ctrl);
  k_gemm_bt<true, false><<<dim3(512 / 64, 16384 / 64), 256, 0, stream>>>(
      hsz + HID, dec_w, dec_b, out, T_STEPS, 512, 512);
}

// Round 5
// 25194.434 us; speedup vs baseline: 1.8626x; 1.8626x over previous
//
#include <hip/hip_runtime.h>
#include <hip/hip_bf16.h>
#include <cstdint>
#include <cstddef>

#define T_STEPS 16384
#define HID 512
#define NSLOTS 32       // worker WGs (512 thr = 8 waves; WG owns 16 h-elems)
#define NLAUNCH 256     // over-launch; round-robin places ~32 WGs per XCD
#define ESC_ITERS 1024  // watchdog polls before escalating to far sync

typedef float f32x4 __attribute__((ext_vector_type(4)));
typedef float f32x2 __attribute__((ext_vector_type(2)));

// ---------------------------------------------------------------------------
// 64-lane sum via DPP (VALU pipe). Result valid in lane 63.
// ---------------------------------------------------------------------------
__device__ __forceinline__ float wave_reduce_sum(float x) {
#define DPP_ADD(ctrl)                                                          \
  x += __int_as_float(__builtin_amdgcn_update_dpp(                             \
      0, __float_as_int(x), (ctrl), 0xF, 0xF, true))
  DPP_ADD(0x111);  // row_shr:1
  DPP_ADD(0x112);  // row_shr:2
  DPP_ADD(0x114);  // row_shr:4
  DPP_ADD(0x118);  // row_shr:8
  DPP_ADD(0x142);  // row_bcast:15
  DPP_ADD(0x143);  // row_bcast:31 -> lane63 = total
#undef DPP_ADD
  return x;
}

__device__ __forceinline__ float fsigmoid(float x) {
  return __builtin_amdgcn_rcpf(1.f + __expf(-x));
}
__device__ __forceinline__ float ftanh(float x) {
  return 1.f - 2.f * __builtin_amdgcn_rcpf(1.f + __expf(2.f * x));
}

// ---------------------------------------------------------------------------
// Poll 8 floats (2 x dwordx4): near = sc0 (XCD-local L2 coherence point),
// far = sc0 sc1 (L3/device). Loads + vmcnt in ONE asm block (no reorder).
// ---------------------------------------------------------------------------
__device__ __forceinline__ void poll_near(const float* a, f32x4& x, f32x4& y) {
  f32x4 u, v;
  asm volatile(
      "global_load_dwordx4 %0, %[p], off sc0\n\t"
      "global_load_dwordx4 %1, %[p], off offset:1024 sc0\n\t"
      "s_waitcnt vmcnt(0)"
      : "=&v"(u), "=&v"(v) : [p] "v"(a) : "memory");
  x = u; y = v;
}
__device__ __forceinline__ void poll_far(const float* a, f32x4& x, f32x4& y) {
  f32x4 u, v;
  asm volatile(
      "global_load_dwordx4 %0, %[p], off sc0 sc1\n\t"
      "global_load_dwordx4 %1, %[p], off offset:1024 sc0 sc1\n\t"
      "s_waitcnt vmcnt(0)"
      : "=&v"(u), "=&v"(v) : [p] "v"(a) : "memory");
  x = u; y = v;
}

// ---------------------------------------------------------------------------
// Prep: hsz[0][:]=0, hsz[1..T][:]=sentinel 2.0f (|h|<1 strictly -> 2.0 is an
// unreachable value-sync token). bc = w_ih@enc_b + b_ih.
// ctrl: [0]=counter, [1..256]=census(-1), [257..512]=assign(-2).
// ---------------------------------------------------------------------------
__global__ void k_prep(float* __restrict__ hsz, float* __restrict__ bc,
                       int* __restrict__ ctrl,
                       const float* __restrict__ w_ih,
                       const float* __restrict__ enc_b,
                       const float* __restrict__ b_ih) {
  const int gid = blockIdx.x * blockDim.x + threadIdx.x;
  const int gsz = gridDim.x * blockDim.x;
  float4* h4 = reinterpret_cast<float4*>(hsz);
  const float4 zer = make_float4(0.f, 0.f, 0.f, 0.f);
  const float4 sen = make_float4(2.f, 2.f, 2.f, 2.f);
  const int n4 = (T_STEPS + 1) * HID / 4;
  for (int i = gid; i < n4; i += gsz) h4[i] = (i < HID / 4) ? zer : sen;
  if (gid == 0) ctrl[0] = 0;
  if (gid >= 1 && gid < 1 + NLAUNCH) ctrl[gid] = -1;                 // census
  if (gid >= 1 + NLAUNCH && gid < 1 + 2 * NLAUNCH) ctrl[gid] = -2;   // assign
  if (gid < 3 * HID) {
    float acc = b_ih[gid];
    const float* wr = w_ih + (size_t)gid * HID;
    for (int j = 0; j < HID; ++j) acc = fmaf(wr[j], enc_b[j], acc);
    bc[gid] = acc;
  }
}

// ---------------------------------------------------------------------------
// 512x512 f32 transpose (enc_w -> enc_w^T).
// ---------------------------------------------------------------------------
__global__ void k_transpose512(const float* __restrict__ in, float* __restrict__ out) {
  __shared__ float tile[32][33];
  const int bx = blockIdx.x * 32, by = blockIdx.y * 32;
  const int x = threadIdx.x, y = threadIdx.y;  // block (32,8)
#pragma unroll
  for (int i = 0; i < 32; i += 8) tile[y + i][x] = in[(size_t)(by + y + i) * 512 + bx + x];
  __syncthreads();
#pragma unroll
  for (int i = 0; i < 32; i += 8) out[(size_t)(bx + y + i) * 512 + by + x] = tile[x][y + i];
}

// ---------------------------------------------------------------------------
// f32 GEMM, C[M,N] = A[M,K] @ B[N,K]^T (+ bias[n]); out f32 or bf16.
// ---------------------------------------------------------------------------
template <bool ADD_BIAS, bool OUT_BF16>
__global__ __launch_bounds__(256) void k_gemm_bt(
    const float* __restrict__ A, const float* __restrict__ B,
    const float* __restrict__ bias, void* __restrict__ C,
    int M, int N, int K) {
  __shared__ float As[16][68];
  __shared__ float Bs[16][68];
  const int n0 = blockIdx.x * 64;
  const int m0 = blockIdx.y * 64;
  const int tid = (int)threadIdx.x;
  const int tx = tid & 15, ty = tid >> 4;
  const int lr = tid >> 2;
  const int lc = (tid & 3) * 4;

  float acc[4][4] = {};
  for (int k0 = 0; k0 < K; k0 += 16) {
    const float4 a4 = *reinterpret_cast<const float4*>(A + (size_t)(m0 + lr) * K + k0 + lc);
    const float4 b4 = *reinterpret_cast<const float4*>(B + (size_t)(n0 + lr) * K + k0 + lc);
    __syncthreads();
    As[lc + 0][lr] = a4.x; As[lc + 1][lr] = a4.y; As[lc + 2][lr] = a4.z; As[lc + 3][lr] = a4.w;
    Bs[lc + 0][lr] = b4.x; Bs[lc + 1][lr] = b4.y; Bs[lc + 2][lr] = b4.z; Bs[lc + 3][lr] = b4.w;
    __syncthreads();
#pragma unroll
    for (int kk = 0; kk < 16; ++kk) {
      const float4 av = *reinterpret_cast<const float4*>(&As[kk][ty * 4]);
      const float4 bv = *reinterpret_cast<const float4*>(&Bs[kk][tx * 4]);
      const float a[4] = {av.x, av.y, av.z, av.w};
      const float b[4] = {bv.x, bv.y, bv.z, bv.w};
#pragma unroll
      for (int i = 0; i < 4; ++i)
#pragma unroll
        for (int j = 0; j < 4; ++j) acc[i][j] = fmaf(a[i], b[j], acc[i][j]);
    }
  }

  float bv[4] = {0.f, 0.f, 0.f, 0.f};
  if (ADD_BIAS) {
#pragma unroll
    for (int j = 0; j < 4; ++j) bv[j] = bias[n0 + tx * 4 + j];
  }
#pragma unroll
  for (int i = 0; i < 4; ++i) {
    const int m = m0 + ty * 4 + i;
    if (OUT_BF16) {
      __hip_bfloat16* Cb = (__hip_bfloat16*)C;
#pragma unroll
      for (int j = 0; j < 4; ++j)
        Cb[(size_t)m * N + n0 + tx * 4 + j] = __float2bfloat16(acc[i][j] + bv[j]);
    } else {
      float4 v;
      v.x = acc[i][0] + bv[0]; v.y = acc[i][1] + bv[1];
      v.z = acc[i][2] + bv[2]; v.w = acc[i][3] + bv[3];
      *reinterpret_cast<float4*>((float*)C + (size_t)m * N + n0 + tx * 4) = v;
    }
  }
}

// ---------------------------------------------------------------------------
// Scan main loop. WG `slot` owns h elems [16*slot, 16*slot+16); wave wv owns
// elems {16*slot+2wv, +1}. Structure per step:
//   wave0: poll row t (near L2 / far L3) -> LDS  | others: wait at barrier
//   barrier; all waves: LDS -> regs, 6 rowdots (DPP), gates at lane63,
//   lane63 -> gather LDS; barrier; wave0 lanes0-15: publish 64B line.
//   wave1 dead-loads row t+2 (prefetch sentinel line into L2).
// Watchdog: after ESC_ITERS failed polls, latch esc, republish own chunk
// far, all-far thereafter (cascading self-heal; deadlock-free).
// ---------------------------------------------------------------------------
template <bool XL>
__device__ void scan_loop(int slot, int wv, int lane,
                          const float* __restrict__ w_hh,
                          const uint32_t* __restrict__ ig32,
                          const float* __restrict__ b_n,
                          float* __restrict__ hsz,
                          float* lds_h, float* gather) {
  const int e0 = slot * 16 + 2 * wv;

  // wA[i] pairs h[4*lane + c]; wB[i] pairs h[256 + 4*lane + c].
  // rows: i0:r/e0 i1:r/e1 i2:z/e0 i3:z/e1 i4:n/e0 i5:n/e1
  f32x4 wA[6], wB[6];
#pragma unroll
  for (int i = 0; i < 6; ++i) {
    const float* wrow = w_hh + (size_t)((i >> 1) * HID + e0 + (i & 1)) * HID;
#pragma unroll
    for (int c = 0; c < 4; ++c) {
      wA[i][c] = wrow[4 * lane + c];
      wB[i][c] = wrow[256 + 4 * lane + c];
    }
  }

  float bn0 = 0.f, bn1 = 0.f, h0 = 0.f, h1 = 0.f;
  if (lane == 63) { bn0 = b_n[e0]; bn1 = b_n[e0 + 1]; }

  // ig pipeline, two steps deep (named regs; no runtime indexing).
  uint32_t gAr = 0, gAz = 0, gAn = 0, gBr = 0, gBz = 0, gBn = 0;
  if (lane == 63) {
    const uint32_t* r0 = ig32 + (e0 >> 1);
    gAr = r0[0]; gAz = r0[256]; gAn = r0[512];
    const uint32_t* r1 = r0 + 768;
    gBr = r1[0]; gBz = r1[256]; gBn = r1[512];
  }

  bool esc = false;  // wave0-uniform escalation latch (XL only)

#pragma unroll 1
  for (int t = 0; t < T_STEPS; ++t) {
    asm volatile("" : "+v"(wA[0]), "+v"(wA[1]), "+v"(wA[2]), "+v"(wA[3]),
                      "+v"(wA[4]), "+v"(wA[5]), "+v"(wB[0]), "+v"(wB[1]),
                      "+v"(wB[2]), "+v"(wB[3]), "+v"(wB[4]), "+v"(wB[5]));

    // ---- phase 1: wave0 acquires row t into LDS
    if (wv == 0) {
      f32x4 hva = {0.f, 0.f, 0.f, 0.f}, hvb = {0.f, 0.f, 0.f, 0.f};
      if (t > 0) {
        const float* p = hsz + (size_t)t * HID + 4 * lane;
        hva = (f32x4)2.f; hvb = (f32x4)2.f;
        int iters = 0;
        for (;;) {
          f32x4 ta, tb;
          if (XL && !esc) poll_near(p, ta, tb); else poll_far(p, ta, tb);
          // monotone merge: keep first-seen real value, retry sentinels
#pragma unroll
          for (int c = 0; c < 4; ++c) {
            hva[c] = (hva[c] < 1.5f) ? hva[c] : ta[c];
            hvb[c] = (hvb[c] < 1.5f) ? hvb[c] : tb[c];
          }
          bool ok = (hva[0] < 1.5f) & (hva[1] < 1.5f) & (hva[2] < 1.5f) &
                    (hva[3] < 1.5f) & (hvb[0] < 1.5f) & (hvb[1] < 1.5f) &
                    (hvb[2] < 1.5f) & (hvb[3] < 1.5f);
          if (__all(ok)) break;
          ++iters;
          if (iters > 1) __builtin_amdgcn_s_sleep(1);  // throttle the L2
          if (XL && !esc && iters > ESC_ITERS) {
            esc = true;  // self-heal: republish our row-t chunk device-wide
            if (lane < 16) {
              float rv = gather[lane];
              float* rd = hsz + (size_t)t * HID + slot * 16 + lane;
              asm volatile("global_store_dword %0, %1, off sc0 sc1"
                           :: "v"(rd), "v"(rv) : "memory");
            }
          }
        }
      }
      *reinterpret_cast<f32x4*>(&lds_h[4 * lane]) = hva;
      *reinterpret_cast<f32x4*>(&lds_h[256 + 4 * lane]) = hvb;
    }
    __syncthreads();

    // ---- prefetch: wave1 pulls row t+2's sentinel line into L2 (dead load)
    if (wv == 1 && t + 2 <= T_STEPS) {
      const float* pf = hsz + (size_t)(t + 2) * HID + 4 * lane;
      f32x4 d1 = *reinterpret_cast<const f32x4*>(pf);
      f32x4 d2 = *reinterpret_cast<const f32x4*>(pf + 256);
      asm volatile("" :: "v"(d1), "v"(d2));
    }

    // ---- phase 2: all waves compute from LDS
    const f32x4 hva = *reinterpret_cast<const f32x4*>(&lds_h[4 * lane]);
    const f32x4 hvb = *reinterpret_cast<const f32x4*>(&lds_h[256 + 4 * lane]);

    // issue ig row t+2 now (lands during next steps' waits)
    uint32_t gCr = 0, gCz = 0, gCn = 0;
    if (lane == 63) {
      const int tn = (t + 2 < T_STEPS) ? t + 2 : T_STEPS - 1;
      const uint32_t* rn = ig32 + (size_t)tn * 768 + (e0 >> 1);
      gCr = rn[0]; gCz = rn[256]; gCn = rn[512];
    }

    float s0, s1, s2, s3, s4, s5;
    {
      float a;
#define ROWDOT(i, dst)                                                         \
      a = 0.f;                                                                 \
      a = fmaf(wA[i][0], hva[0], a); a = fmaf(wA[i][1], hva[1], a);            \
      a = fmaf(wA[i][2], hva[2], a); a = fmaf(wA[i][3], hva[3], a);            \
      a = fmaf(wB[i][0], hvb[0], a); a = fmaf(wB[i][1], hvb[1], a);            \
      a = fmaf(wB[i][2], hvb[2], a); a = fmaf(wB[i][3], hvb[3], a);            \
      dst = wave_reduce_sum(a)
      ROWDOT(0, s0); ROWDOT(1, s1); ROWDOT(2, s2);
      ROWDOT(3, s3); ROWDOT(4, s4); ROWDOT(5, s5);
#undef ROWDOT
    }

    if (lane == 63) {
      const float ir0 = __uint_as_float(gAr << 16);
      const float ir1 = __uint_as_float(gAr & 0xffff0000u);
      const float iz0 = __uint_as_float(gAz << 16);
      const float iz1 = __uint_as_float(gAz & 0xffff0000u);
      const float in0 = __uint_as_float(gAn << 16);
      const float in1 = __uint_as_float(gAn & 0xffff0000u);

      const float r0 = fsigmoid(ir0 + s0);
      const float r1 = fsigmoid(ir1 + s1);
      const float z0 = fsigmoid(iz0 + s2);
      const float z1 = fsigmoid(iz1 + s3);
      const float n0 = ftanh(in0 + r0 * (s4 + bn0));
      const float n1 = ftanh(in1 + r1 * (s5 + bn1));
      h0 = n0 + z0 * (h0 - n0);
      h1 = n1 + z1 * (h1 - n1);
      *reinterpret_cast<f32x2*>(&gather[2 * wv]) = (f32x2){h0, h1};
    }
    __syncthreads();

    // ---- phase 3: wave0 publishes the WG's 16 values as ONE 64B line
    if (wv == 0 && lane < 16) {
      const float v = gather[lane];
      float* dst = hsz + (size_t)(t + 1) * HID + slot * 16 + lane;
      if (XL && !esc)
        asm volatile("global_store_dword %0, %1, off sc0"
                     :: "v"(dst), "v"(v) : "memory");
      else
        asm volatile("global_store_dword %0, %1, off sc0 sc1"
                     :: "v"(dst), "v"(v) : "memory");
    }

    gAr = gBr; gAz = gBz; gAn = gBn;
    gBr = gCr; gBz = gCz; gBn = gCn;
  }
}

// ---------------------------------------------------------------------------
// Persistent scan with single-leader census placement (terminating by
// construction; scan self-heals if XCC info was wrong).
// ---------------------------------------------------------------------------
__global__ __launch_bounds__(512) void k_scan(
    const float* __restrict__ w_hh, const __hip_bfloat16* __restrict__ igb,
    const float* __restrict__ b_n, float* __restrict__ hsz,
    int* __restrict__ ctrl) {
  int* counter = ctrl;
  int* census  = ctrl + 1;
  int* assign  = ctrl + 1 + NLAUNCH;
  __shared__ int s_assign;
  __shared__ float lds_h[HID];
  __shared__ float gather[16];

  int myxcc;
  asm("s_getreg_b32 %0, hwreg(HW_REG_XCC_ID)" : "=s"(myxcc));
  const int bid = (int)blockIdx.x;

  if (threadIdx.x == 0) {
    __hip_atomic_store(&census[bid], myxcc, __ATOMIC_RELAXED,
                       __HIP_MEMORY_SCOPE_AGENT);
    __hip_atomic_fetch_add(counter, 1, __ATOMIC_RELEASE,
                           __HIP_MEMORY_SCOPE_AGENT);
    if (bid == 0) {
      const uint64_t t0 = __builtin_amdgcn_s_memrealtime();
      int cnt;
      for (;;) {
        cnt = __hip_atomic_load(counter, __ATOMIC_ACQUIRE,
                                __HIP_MEMORY_SCOPE_AGENT);
        if (cnt >= NLAUNCH) break;
        if (cnt >= NSLOTS &&
            (__builtin_amdgcn_s_memrealtime() - t0) > 20000) break;  // ~200us
        __builtin_amdgcn_s_sleep(1);
      }
      int hist[8] = {0, 0, 0, 0, 0, 0, 0, 0};
      for (int i = 0; i < NLAUNCH; ++i) {
        int c = __hip_atomic_load(&census[i], __ATOMIC_RELAXED,
                                  __HIP_MEMORY_SCOPE_AGENT);
        if (c >= 0 && c < 8) ++hist[c];
      }
      int pick = -1;
      for (int x = 0; x < 8; ++x)
        if (pick < 0 && hist[x] >= NSLOTS) pick = x;
      const int mode = (pick >= 0) ? 1 : 0;
      int slot = 0;
      for (int i = 0; i < NLAUNCH; ++i) {
        int c = __hip_atomic_load(&census[i], __ATOMIC_RELAXED,
                                  __HIP_MEMORY_SCOPE_AGENT);
        int a = -1;
        const bool take = (pick >= 0) ? (c == pick) : (c >= 0);
        if (take && slot < NSLOTS) { a = slot * 2 + mode; ++slot; }
        __hip_atomic_store(&assign[i], a, __ATOMIC_RELAXED,
                           __HIP_MEMORY_SCOPE_AGENT);
      }
    }
    int a;
    do {
      a = __hip_atomic_load(&assign[bid], __ATOMIC_ACQUIRE,
                            __HIP_MEMORY_SCOPE_AGENT);
      if (a == -2) __builtin_amdgcn_s_sleep(1);
    } while (a == -2);
    s_assign = a;
  }
  __syncthreads();
  const int a = s_assign;
  if (a < 0) return;
  const int slot = a >> 1, mode = a & 1;

  const int wv = (int)threadIdx.x >> 6;    // 0..7
  const int lane = (int)threadIdx.x & 63;
  const uint32_t* ig32 = reinterpret_cast<const uint32_t*>(igb);

  if (mode) scan_loop<true>(slot, wv, lane, w_hh, ig32, b_n, hsz, lds_h, gather);
  else      scan_loop<false>(slot, wv, lane, w_hh, ig32, b_n, hsz, lds_h, gather);
}

// ---------------------------------------------------------------------------
extern "C" void kernel_launch(void* const* d_in, const int* in_sizes, int n_in,
                              void* d_out, int out_size, void* d_ws, size_t ws_size,
                              hipStream_t stream) {
  (void)in_sizes; (void)n_in; (void)out_size; (void)ws_size;
  const float* x     = (const float*)d_in[0];
  const float* enc_w = (const float*)d_in[1];
  const float* enc_b = (const float*)d_in[2];
  const float* w_ih  = (const float*)d_in[3];
  const float* w_hh  = (const float*)d_in[4];
  const float* b_ih  = (const float*)d_in[5];
  const float* b_n   = (const float*)d_in[6];
  const float* dec_w = (const float*)d_in[7];
  const float* dec_b = (const float*)d_in[8];
  float* out = (float*)d_out;

  uintptr_t p = (uintptr_t)d_ws;
  auto carve = [&](size_t bytes) {
    void* r = (void*)p;
    p += (bytes + 255) & ~(size_t)255;
    return r;
  };
  int* ctrl           = (int*)carve((size_t)(1 + 2 * NLAUNCH) * 4);
  float* encwT        = (float*)carve((size_t)512 * 512 * 4);
  float* Wc           = (float*)carve((size_t)1536 * 512 * 4);
  float* bc           = (float*)carve((size_t)1536 * 4);
  __hip_bfloat16* igb = (__hip_bfloat16*)carve((size_t)T_STEPS * 1536 * 2);
  float* hsz          = (float*)carve((size_t)(T_STEPS + 1) * HID * 4);

  k_prep<<<1024, 256, 0, stream>>>(hsz, bc, ctrl, w_ih, enc_b, b_ih);
  k_transpose512<<<dim3(16, 16), dim3(32, 8), 0, stream>>>(enc_w, encwT);
  k_gemm_bt<false, false><<<dim3(512 / 64, 1536 / 64), 256, 0, stream>>>(
      w_ih, encwT, nullptr, Wc, 1536, 512, 512);
  k_gemm_bt<true, true><<<dim3(1536 / 64, 16384 / 64), 256, 0, stream>>>(
      x, Wc, bc, igb, T_STEPS, 1536, 512);
  k_scan<<<NLAUNCH, 512, 0, stream>>>(w_hh, igb, b_n, hsz, ctrl);
  k_gemm_bt<true, false><<<dim3(512 / 64, 16384 / 64), 256, 0, stream>>>(
      hsz + HID, dec_w, dec_b, out, T_STEPS, 512, 512);
}